// Round 12
// baseline (139.062 us; speedup 1.0000x reference)
//
#include <hip/hip_runtime.h>
#include <math.h>

typedef short bf16x8 __attribute__((ext_vector_type(8)));
typedef short bf16x4 __attribute__((ext_vector_type(4)));
typedef float floatx4 __attribute__((ext_vector_type(4)));
typedef float floatx2 __attribute__((ext_vector_type(2)));
typedef float floatx16 __attribute__((ext_vector_type(16)));

#define NB   16384
#define H8   8
#define ND   256
#define NHD  128
#define NK   384

__device__ __forceinline__ unsigned short f2bf(float f) {
  unsigned int u = __float_as_uint(f);
  u += 0x7FFFu + ((u >> 16) & 1u);
  return (unsigned short)(u >> 16);
}
__device__ __forceinline__ float bf2f(unsigned short s) {
  return __uint_as_float(((unsigned int)s) << 16);
}
__device__ __forceinline__ float fast_sigmoid(float z) {
  z = fminf(fmaxf(z, -60.f), 60.f);
  return __builtin_amdgcn_rcpf(1.f + __expf(-z));
}
__device__ __forceinline__ float fast_tanh(float s) {
  s = fminf(fmaxf(s, -9.f), 9.f);
  float e = __expf(2.f * s);
  return (e - 1.f) * __builtin_amdgcn_rcpf(e + 1.f);
}
// 16B-granular LDS swizzle: spread frag-slot (s = idx>>6) into lane-low bits.
__device__ __forceinline__ int swz(int idx16) {
  return idx16 ^ ((idx16 >> 6) & 7);
}

// ================= fragment-packed path (32x32x16) =================
#define WTP (H8 * 24 * 4 * 512)   // tanh_w hi frags
#define WOP (H8 * 8 * 8 * 512)    // out_w frags
#define XFP (NB * ND)             // x hi frags
#define WS_NEED3 ((size_t)(WTP + WOP + XFP) * 2)

// blocks 0..191: tanh_w transpose; 192..255: out_w; 256..2303: x-hi pack
__global__ void prep3c(const float* __restrict__ tanh_w,
                       const float* __restrict__ out_w,
                       const float* __restrict__ x,
                       short* __restrict__ wtp_hi,
                       short* __restrict__ wop,
                       short* __restrict__ xfh) {
  __shared__ float tile[16 * 260];
  const int t = threadIdx.x;
  const int b = blockIdx.x;
  if (b < 192) {
    int head = b / 24, ks = b % 24;
    const float* slab = tanh_w + ((size_t)head * NK + ks * 16) * NHD;
#pragma unroll
    for (int it = 0; it < 2; ++it) {
      int i = it * 256 + t;
      floatx4 v = reinterpret_cast<const floatx4*>(slab)[i];
      int r = i >> 5, c4 = i & 31;
      *reinterpret_cast<floatx4*>(&tile[r * 132 + c4 * 4]) = v;
    }
    __syncthreads();
    int ct = t >> 6, l = t & 63;
    bf16x8 hi8;
#pragma unroll
    for (int j = 0; j < 8; ++j) {
      float w = tile[((l >> 5) * 8 + j) * 132 + ct * 32 + (l & 31)];
      hi8[j] = (short)f2bf(w);
    }
    size_t dst = ((((size_t)head * 24 + ks) * 4 + ct) * 64 + l) * 8;
    *reinterpret_cast<bf16x8*>(wtp_hi + dst) = hi8;
  } else if (b < 256) {
    int head = (b - 192) / 8, ks = (b - 192) % 8;
    const float* slab = out_w + ((size_t)head * NHD + ks * 16) * ND;
#pragma unroll
    for (int it = 0; it < 4; ++it) {
      int i = it * 256 + t;
      floatx4 v = reinterpret_cast<const floatx4*>(slab)[i];
      int r = i >> 6, c4 = i & 63;
      *reinterpret_cast<floatx4*>(&tile[r * 260 + c4 * 4]) = v;
    }
    __syncthreads();
#pragma unroll
    for (int u = 0; u < 2; ++u) {
      int idx = u * 256 + t;
      int ct = idx >> 6, l = idx & 63;
      bf16x8 o8;
#pragma unroll
      for (int j = 0; j < 8; ++j) {
        float w = tile[((l >> 5) * 8 + j) * 260 + ct * 32 + (l & 31)];
        o8[j] = (short)f2bf(w);
      }
      size_t dst = ((((size_t)head * 8 + ks) * 8 + ct) * 64 + l) * 8;
      *reinterpret_cast<bf16x8*>(wop + dst) = o8;
    }
  } else {
    // x-hi pack: one 8-float chunk per thread
    int i = (b - 256) * 256 + t;
    int bb = i >> 5, c0 = (i & 31) * 8;
    const float* xp = x + (size_t)bb * ND + c0;
    floatx4 v0 = *reinterpret_cast<const floatx4*>(xp);
    floatx4 v1 = *reinterpret_cast<const floatx4*>(xp + 4);
    bf16x8 h8;
#pragma unroll
    for (int j = 0; j < 4; ++j) {
      h8[j] = (short)f2bf(v0[j]);
      h8[4 + j] = (short)f2bf(v1[j]);
    }
    int dst = ((bb >> 5) * 16 + (c0 >> 4)) * 512 +
              (((c0 >> 3) & 1) * 32 + (bb & 31)) * 8;
    *reinterpret_cast<bf16x8*>(xfh + dst) = h8;
  }
}

// 256-thread block, 4 waves (one per 32-col quad cq); BM=64 = 2 row-groups/wave.
// Gates computed in-kernel (exact f32); g folded into h staging; swizzled LDS.
__global__ __launch_bounds__(256, 4) void gru3(
    const float* __restrict__ h, const float* __restrict__ x,
    const float* __restrict__ sig_w, const float* __restrict__ sig_b,
    const float* __restrict__ tanh_b, const float* __restrict__ out_b,
    const short* __restrict__ wtp_hi, const short* __restrict__ wop,
    const short* __restrict__ xfh,
    float* __restrict__ out, float* __restrict__ out_nh) {
  __shared__ __align__(16) short AhH[16 * 512];  // 16 KB: g*h hi frags -> new_h frags
  __shared__ __align__(16) short AhL[16 * 512];  // 16 KB: g*h lo frags
  __shared__ float gbuf[64], pbuf[64];

  const int t = threadIdx.x;
  const int lane = t & 63;
  const int cq = t >> 6;
  const int l31 = lane & 31;
  const int lh = lane >> 5;
  const int head = (int)(blockIdx.x >> 8);
  const int rb = (int)(blockIdx.x & 255);
  const long rowbase = (long)rb * 64;

  // ---- issue staging h loads early (held in regs across gate phase) ----
  floatx4 hreg[4][2];
  int srow[4], skc[4];
#pragma unroll
  for (int it = 0; it < 4; ++it) {
    int gi = it * 256 + t;
    int row = gi >> 4, kc = gi & 15;
    srow[it] = row; skc[it] = kc;
    const float* hp = h + ((rowbase + row) * H8 + head) * NHD + kc * 8;
    hreg[it][0] = *reinterpret_cast<const floatx4*>(hp);
    hreg[it][1] = *reinterpret_cast<const floatx4*>(hp + 4);
  }

  // ---- gates in exact f32: 4 threads/row, contiguous 96-k spans ----
  {
    int r = t >> 2, u = t & 3;
    const float* hrow = h + ((rowbase + r) * H8 + head) * NHD;
    const float* xrow = x + (rowbase + r) * ND;
    const float* wsp = sig_w + (size_t)head * NK * 2;
    float a0 = 0.f, a1 = 0.f;
#pragma unroll
    for (int i = 0; i < 24; ++i) {
      int k = u * 96 + i * 4;
      floatx4 av = (k < 128)
          ? *reinterpret_cast<const floatx4*>(hrow + k)
          : *reinterpret_cast<const floatx4*>(xrow + (k - 128));
      floatx4 w01 = *reinterpret_cast<const floatx4*>(wsp + k * 2);
      floatx4 w23 = *reinterpret_cast<const floatx4*>(wsp + k * 2 + 4);
      a0 += av[0] * w01[0] + av[1] * w01[2] + av[2] * w23[0] + av[3] * w23[2];
      a1 += av[0] * w01[1] + av[1] * w01[3] + av[2] * w23[1] + av[3] * w23[3];
    }
    a0 += __shfl_xor(a0, 1); a0 += __shfl_xor(a0, 2);
    a1 += __shfl_xor(a1, 1); a1 += __shfl_xor(a1, 2);
    if (u == 0) {
      gbuf[r] = fast_sigmoid(a0 + sig_b[head * 2 + 0]);
      pbuf[r] = fast_sigmoid(a1 + sig_b[head * 2 + 1]);
    }
  }
  __syncthreads();

  // ---- stage split(g*h) into swizzled frag LDS ----
#pragma unroll
  for (int it = 0; it < 4; ++it) {
    int row = srow[it], kc = skc[it];
    float g = gbuf[row];
    bf16x8 hi8, lo8;
#pragma unroll
    for (int j = 0; j < 4; ++j) {
      float s0 = g * hreg[it][0][j];
      unsigned short hb = f2bf(s0);
      hi8[j] = (short)hb; lo8[j] = (short)f2bf(s0 - bf2f(hb));
      float s1 = g * hreg[it][1][j];
      unsigned short hb2 = f2bf(s1);
      hi8[4 + j] = (short)hb2; lo8[4 + j] = (short)f2bf(s1 - bf2f(hb2));
    }
    int rg = row >> 5, row32 = row & 31;
    int chunk = (rg * 8 + (kc >> 1)) * 64 + (kc & 1) * 32 + row32;
    int sc = swz(chunk);
    *reinterpret_cast<bf16x8*>(&AhH[sc * 8]) = hi8;
    *reinterpret_cast<bf16x8*>(&AhL[sc * 8]) = lo8;
  }
  __syncthreads();

  const short* __restrict__ xh0 = xfh + ((size_t)(rb * 2 + 0) * 16 * 512) + lane * 8;
  const short* __restrict__ xh1 = xfh + ((size_t)(rb * 2 + 1) * 16 * 512) + lane * 8;
  const short* __restrict__ bh_p = wtp_hi + (((size_t)head * 24 * 4 + cq) * 512) + lane * 8;

  // ---- tanh matmul: acc = (g*h)@Wt_h (2-term) + x@Wt_x (hi only) ----
  floatx16 acc0, acc1;
#pragma unroll
  for (int z = 0; z < 16; ++z) { acc0[z] = 0.f; acc1[z] = 0.f; }

  bf16x8 bhA = *reinterpret_cast<const bf16x8*>(bh_p);
  bf16x8 bhB = *reinterpret_cast<const bf16x8*>(bh_p + 2048);
#pragma unroll
  for (int ks = 0; ks < 8; ++ks) {
    bf16x8 bh = bhA; bhA = bhB;
    bhB = *reinterpret_cast<const bf16x8*>(bh_p + (ks + 2) * 2048);
    bf16x8 a0h = *reinterpret_cast<const bf16x8*>(&AhH[swz(ks * 64 + lane) * 8]);
    bf16x8 a0l = *reinterpret_cast<const bf16x8*>(&AhL[swz(ks * 64 + lane) * 8]);
    bf16x8 a1h = *reinterpret_cast<const bf16x8*>(&AhH[swz((8 + ks) * 64 + lane) * 8]);
    bf16x8 a1l = *reinterpret_cast<const bf16x8*>(&AhL[swz((8 + ks) * 64 + lane) * 8]);
    acc0 = __builtin_amdgcn_mfma_f32_32x32x16_bf16(a0h, bh, acc0, 0, 0, 0);
    acc0 = __builtin_amdgcn_mfma_f32_32x32x16_bf16(a0l, bh, acc0, 0, 0, 0);
    acc1 = __builtin_amdgcn_mfma_f32_32x32x16_bf16(a1h, bh, acc1, 0, 0, 0);
    acc1 = __builtin_amdgcn_mfma_f32_32x32x16_bf16(a1l, bh, acc1, 0, 0, 0);
  }
  {
    bf16x8 x0A = *reinterpret_cast<const bf16x8*>(xh0);
    bf16x8 x1A = *reinterpret_cast<const bf16x8*>(xh1);
    bf16x8 x0B = *reinterpret_cast<const bf16x8*>(xh0 + 512);
    bf16x8 x1B = *reinterpret_cast<const bf16x8*>(xh1 + 512);
#pragma unroll
    for (int xk = 0; xk < 16; ++xk) {
      const int ks = 8 + xk;
      bf16x8 bh = bhA; bhA = bhB;
      if (ks + 2 < 24) bhB = *reinterpret_cast<const bf16x8*>(bh_p + (ks + 2) * 2048);
      bf16x8 x0 = x0A, x1 = x1A;
      x0A = x0B; x1A = x1B;
      if (xk + 2 < 16) {
        x0B = *reinterpret_cast<const bf16x8*>(xh0 + (xk + 2) * 512);
        x1B = *reinterpret_cast<const bf16x8*>(xh1 + (xk + 2) * 512);
      }
      acc0 = __builtin_amdgcn_mfma_f32_32x32x16_bf16(x0, bh, acc0, 0, 0, 0);
      acc1 = __builtin_amdgcn_mfma_f32_32x32x16_bf16(x1, bh, acc1, 0, 0, 0);
    }
  }
  __syncthreads();   // all AhH/AhL reads done before new_h overwrites

  // ---- GRU epilogue: cand = tanh(acc + tb); hv from h (L2-warm) ----
  const int col = cq * 32 + l31;
  const float tb = tanh_b[head * NHD + col];
  const float* __restrict__ hcol = h + (rowbase * H8 + head) * NHD + col;
#define EPI(RG, ACC)                                                          \
  {                                                                           \
    _Pragma("unroll")                                                         \
    for (int reg = 0; reg < 16; ++reg) {                                      \
      int crow = (reg & 3) + 8 * (reg >> 2) + 4 * lh;                         \
      int row = RG * 32 + crow;                                               \
      float p = pbuf[row];                                                    \
      float cand = fast_tanh(ACC[reg] + tb);                                  \
      float hv = hcol[(size_t)row * (H8 * NHD)];                              \
      float nh = hv + p * (cand - hv);                                        \
      int el16 = (RG * 8 + (col >> 4)) * 64 + ((l31 >> 3) & 1) * 32 + crow;   \
      out_nh[((rowbase + row) * H8 + head) * NHD + col] = nh;                 \
      AhH[swz(el16) * 8 + (col & 7)] = (short)f2bf(nh);                       \
    }                                                                         \
  }
  EPI(0, acc0)
  EPI(1, acc1)
#undef EPI
  __syncthreads();

  // ---- out matmul: new_h (in AhH) @ out_w, per row-group ----
  const short* __restrict__ wo_p = wop + (((size_t)head * 64 + cq * 2) * 512) + lane * 8;
  const float ob0 = out_b[head * ND + cq * 64 + l31];
  const float ob1 = out_b[head * ND + cq * 64 + 32 + l31];
#define OUTP(RG)                                                              \
  {                                                                           \
    floatx16 a3a, a3b;                                                        \
    _Pragma("unroll")                                                         \
    for (int z = 0; z < 16; ++z) { a3a[z] = 0.f; a3b[z] = 0.f; }              \
    bf16x8 w0n = *reinterpret_cast<const bf16x8*>(wo_p);                      \
    bf16x8 w1n = *reinterpret_cast<const bf16x8*>(wo_p + 512);                \
    _Pragma("unroll")                                                         \
    for (int ks = 0; ks < 8; ++ks) {                                          \
      bf16x8 w0 = w0n, w1 = w1n;                                              \
      if (ks < 7) {                                                           \
        w0n = *reinterpret_cast<const bf16x8*>(wo_p + (ks + 1) * 4096);       \
        w1n = *reinterpret_cast<const bf16x8*>(wo_p + (ks + 1) * 4096 + 512); \
      }                                                                       \
      bf16x8 a = *reinterpret_cast<const bf16x8*>(&AhH[swz((RG * 8 + ks) * 64 + lane) * 8]); \
      a3a = __builtin_amdgcn_mfma_f32_32x32x16_bf16(a, w0, a3a, 0, 0, 0);     \
      a3b = __builtin_amdgcn_mfma_f32_32x32x16_bf16(a, w1, a3b, 0, 0, 0);     \
    }                                                                         \
    _Pragma("unroll")                                                         \
    for (int reg = 0; reg < 16; ++reg) {                                      \
      int row = RG * 32 + (reg & 3) + 8 * (reg >> 2) + 4 * lh;                \
      long obase = ((rowbase + row) * H8 + head) * ND;                        \
      out[obase + cq * 64 + l31] = a3a[reg] + ob0;                            \
      out[obase + cq * 64 + 32 + l31] = a3b[reg] + ob1;                       \
    }                                                                         \
  }
  OUTP(0)
  OUTP(1)
#undef OUTP
}

// ================= fallback path (round-2 kernels) =================
#define WT_ELEMS (H8 * NK * NHD)
#define WO_ELEMS (H8 * NHD * ND)

__global__ void prep_kernel(const float* __restrict__ tanh_w,
                            const float* __restrict__ out_w,
                            short* __restrict__ wt_hi,
                            short* __restrict__ wt_lo,
                            short* __restrict__ wo) {
  const int total1 = WT_ELEMS;
  const int total2 = WO_ELEMS;
  for (int i = blockIdx.x * blockDim.x + threadIdx.x; i < total1 + total2;
       i += gridDim.x * blockDim.x) {
    if (i < total1) {
      int hh = i / (NK * NHD);
      int rem = i - hh * NK * NHD;
      int k = rem / NHD, n = rem - k * NHD;
      float w = tanh_w[i];
      unsigned short hi = f2bf(w);
      unsigned short lo = f2bf(w - bf2f(hi));
      int dst = hh * (48 * NHD * 8) + (k >> 3) * (NHD * 8) + n * 8 + (k & 7);
      wt_hi[dst] = (short)hi;
      wt_lo[dst] = (short)lo;
    } else {
      int j = i - total1;
      int hh = j / (NHD * ND);
      int rem = j - hh * NHD * ND;
      int k = rem / ND, n = rem - k * ND;
      int dst = hh * (16 * ND * 8) + (k >> 3) * (ND * 8) + n * 8 + (k & 7);
      wo[dst] = (short)f2bf(out_w[j]);
    }
  }
}

#define BM   32
#define NT   512
#define LDA 392
#define LDNH 136

__global__ __launch_bounds__(NT, 4) void gru_main(
    const float* __restrict__ x, const float* __restrict__ h,
    const float* __restrict__ sig_w, const float* __restrict__ sig_b,
    const float* __restrict__ tanh_b, const float* __restrict__ out_b,
    const short* __restrict__ wt_hi, const short* __restrict__ wt_lo,
    const short* __restrict__ wo,
    float* __restrict__ out, float* __restrict__ out_nh) {
  __shared__ __align__(16) short Ahi[BM][LDA];
  __shared__ __align__(16) short Alo[BM][LDA];
  __shared__ __align__(16) short NHL[BM][LDNH];
  __shared__ floatx2 swl[NK];
  __shared__ float gbuf[BM], pbuf[BM];

  const int t = threadIdx.x;
  const int lane = t & 63;
  const int wid = t >> 6;
  const int wrow = wid >> 2;
  const int wcol = wid & 3;
  const int ln = lane & 15;
  const int kg = lane >> 4;
  const int head = blockIdx.x & 7;
  const long rowbase = (long)(blockIdx.x >> 3) * BM;
  const int arow = wrow * 16 + ln;

#pragma unroll
  for (int i = 0; i < 4; ++i) {
    int idx = i * NT + t;
    int r = idx >> 6, c4 = idx & 63;
    floatx4 v = *reinterpret_cast<const floatx4*>(x + (rowbase + r) * ND + c4 * 4);
    bf16x4 hi, lo;
#pragma unroll
    for (int j = 0; j < 4; ++j) {
      unsigned short hb = f2bf(v[j]);
      hi[j] = (short)hb;
      lo[j] = (short)f2bf(v[j] - bf2f(hb));
    }
    *reinterpret_cast<bf16x4*>(&Ahi[r][NHD + c4 * 4]) = hi;
    *reinterpret_cast<bf16x4*>(&Alo[r][NHD + c4 * 4]) = lo;
  }
#pragma unroll
  for (int i = 0; i < 2; ++i) {
    int idx = i * NT + t;
    int r = idx >> 5, c4 = idx & 31;
    floatx4 v = *reinterpret_cast<const floatx4*>(
        h + ((rowbase + r) * H8 + head) * NHD + c4 * 4);
    bf16x4 hi, lo;
#pragma unroll
    for (int j = 0; j < 4; ++j) {
      unsigned short hb = f2bf(v[j]);
      hi[j] = (short)hb;
      lo[j] = (short)f2bf(v[j] - bf2f(hb));
    }
    *reinterpret_cast<bf16x4*>(&Ahi[r][c4 * 4]) = hi;
    *reinterpret_cast<bf16x4*>(&Alo[r][c4 * 4]) = lo;
  }
  if (t < NK)
    swl[t] = *reinterpret_cast<const floatx2*>(sig_w + ((size_t)head * NK + t) * 2);
  __syncthreads();
  {
    int r = t >> 4, u = t & 15;
    float a0 = 0.f, a1 = 0.f;
#pragma unroll
    for (int kk = 0; kk < 24; ++kk) {
      int k = u + kk * 16;
      float a = bf2f((unsigned short)Ahi[r][k]) + bf2f((unsigned short)Alo[r][k]);
      floatx2 w = swl[k];
      a0 += a * w[0];
      a1 += a * w[1];
    }
#pragma unroll
    for (int off = 1; off < 16; off <<= 1) {
      a0 += __shfl_xor(a0, off);
      a1 += __shfl_xor(a1, off);
    }
    if (u == 0) {
      gbuf[r] = fast_sigmoid(a0 + sig_b[head * 2 + 0]);
      pbuf[r] = fast_sigmoid(a1 + sig_b[head * 2 + 1]);
    }
  }
  floatx4 acc1[2] = {{0.f, 0.f, 0.f, 0.f}, {0.f, 0.f, 0.f, 0.f}};
  floatx4 acc2[2] = {{0.f, 0.f, 0.f, 0.f}, {0.f, 0.f, 0.f, 0.f}};
  const size_t wtbase = (size_t)head * (48 * NHD * 8);
#pragma unroll
  for (int ks = 0; ks < 12; ++ks) {
    bf16x8 ahi = *reinterpret_cast<const bf16x8*>(&Ahi[arow][ks * 32 + kg * 8]);
    bf16x8 alo = *reinterpret_cast<const bf16x8*>(&Alo[arow][ks * 32 + kg * 8]);
    floatx4* acc = (ks < 4) ? acc1 : acc2;
#pragma unroll
    for (int cf = 0; cf < 2; ++cf) {
      int n0 = wcol * 32 + cf * 16;
      size_t woff = wtbase + (size_t)(ks * 4 + kg) * (NHD * 8) + (size_t)(n0 + ln) * 8;
      bf16x8 bhi = *reinterpret_cast<const bf16x8*>(wt_hi + woff);
      bf16x8 blo = *reinterpret_cast<const bf16x8*>(wt_lo + woff);
      acc[cf] = __builtin_amdgcn_mfma_f32_16x16x32_bf16(ahi, bhi, acc[cf], 0, 0, 0);
      acc[cf] = __builtin_amdgcn_mfma_f32_16x16x32_bf16(alo, bhi, acc[cf], 0, 0, 0);
      acc[cf] = __builtin_amdgcn_mfma_f32_16x16x32_bf16(ahi, blo, acc[cf], 0, 0, 0);
    }
  }
  __syncthreads();
#pragma unroll
  for (int cf = 0; cf < 2; ++cf) {
    int col = wcol * 32 + cf * 16 + ln;
    float tb = tanh_b[head * NHD + col];
#pragma unroll
    for (int j = 0; j < 4; ++j) {
      int r = wrow * 16 + kg * 4 + j;
      float g = gbuf[r], p = pbuf[r];
      float s = g * acc1[cf][j] + acc2[cf][j] + tb;
      float cand = fast_tanh(s);
      float hv = bf2f((unsigned short)Ahi[r][col]) + bf2f((unsigned short)Alo[r][col]);
      float nh = hv + p * (cand - hv);
      out_nh[((rowbase + r) * H8 + head) * NHD + col] = nh;
      NHL[r][col] = (short)f2bf(nh);
    }
  }
  __syncthreads();
  floatx4 acc3[4] = {{0.f, 0.f, 0.f, 0.f}, {0.f, 0.f, 0.f, 0.f},
                     {0.f, 0.f, 0.f, 0.f}, {0.f, 0.f, 0.f, 0.f}};
  const size_t wobase = (size_t)head * (16 * ND * 8);
#pragma unroll
  for (int ks = 0; ks < 4; ++ks) {
    bf16x8 a = *reinterpret_cast<const bf16x8*>(&NHL[arow][ks * 32 + kg * 8]);
#pragma unroll
    for (int cf = 0; cf < 4; ++cf) {
      int n0 = wcol * 64 + cf * 16;
      size_t woff = wobase + (size_t)(ks * 4 + kg) * (ND * 8) + (size_t)(n0 + ln) * 8;
      bf16x8 bfr = *reinterpret_cast<const bf16x8*>(wo + woff);
      acc3[cf] = __builtin_amdgcn_mfma_f32_16x16x32_bf16(a, bfr, acc3[cf], 0, 0, 0);
    }
  }
#pragma unroll
  for (int cf = 0; cf < 4; ++cf) {
    int col = wcol * 64 + cf * 16 + ln;
    float ob = out_b[head * ND + col];
#pragma unroll
    for (int j = 0; j < 4; ++j) {
      int r = wrow * 16 + kg * 4 + j;
      out[((rowbase + r) * H8 + head) * ND + col] = acc3[cf][j] + ob;
    }
  }
}

extern "C" void kernel_launch(void* const* d_in, const int* in_sizes, int n_in,
                              void* d_out, int out_size, void* d_ws, size_t ws_size,
                              hipStream_t stream) {
  (void)in_sizes; (void)n_in; (void)out_size;
  const float* x      = (const float*)d_in[0];
  const float* h      = (const float*)d_in[1];
  const float* sig_w  = (const float*)d_in[2];
  const float* sig_b  = (const float*)d_in[3];
  const float* tanh_w = (const float*)d_in[4];
  const float* tanh_b = (const float*)d_in[5];
  const float* out_w  = (const float*)d_in[6];
  const float* out_b  = (const float*)d_in[7];

  float* out = (float*)d_out;
  float* out_nh = out + (size_t)NB * H8 * ND;

  if (ws_size >= WS_NEED3) {
    short* wtp_hi = (short*)d_ws;
    short* wop    = wtp_hi + WTP;
    short* xfh    = wop + WOP;
    hipLaunchKernelGGL(prep3c, dim3(256 + 2048), dim3(256), 0, stream,
                       tanh_w, out_w, x, wtp_hi, wop, xfh);
    hipLaunchKernelGGL(gru3, dim3((NB / 64) * H8), dim3(256), 0, stream,
                       h, x, sig_w, sig_b, tanh_b, out_b, wtp_hi, wop, xfh,
                       out, out_nh);
  } else {
    short* wt_hi = (short*)d_ws;
    short* wt_lo = wt_hi + WT_ELEMS;
    short* wo    = wt_lo + WT_ELEMS;
    hipLaunchKernelGGL(prep_kernel, dim3(512), dim3(256), 0, stream,
                       tanh_w, out_w, wt_hi, wt_lo, wo);
    hipLaunchKernelGGL(gru_main, dim3((NB / BM) * H8), dim3(NT), 0, stream,
                       x, h, sig_w, sig_b, tanh_b, out_b, wt_hi, wt_lo, wo,
                       out, out_nh);
  }
}

// Round 13
// 90.729 us; speedup vs baseline: 1.5327x; 1.5327x over previous
//
#include <hip/hip_runtime.h>
#include <math.h>

typedef short bf16x8 __attribute__((ext_vector_type(8)));
typedef short bf16x4 __attribute__((ext_vector_type(4)));
typedef float floatx4 __attribute__((ext_vector_type(4)));
typedef float floatx2 __attribute__((ext_vector_type(2)));
typedef float floatx16 __attribute__((ext_vector_type(16)));

#define NB   16384
#define H8   8
#define ND   256
#define NHD  128
#define NK   384

__device__ __forceinline__ unsigned short f2bf(float f) {
  unsigned int u = __float_as_uint(f);
  u += 0x7FFFu + ((u >> 16) & 1u);
  return (unsigned short)(u >> 16);
}
__device__ __forceinline__ float bf2f(unsigned short s) {
  return __uint_as_float(((unsigned int)s) << 16);
}
__device__ __forceinline__ float fast_sigmoid(float z) {
  z = fminf(fmaxf(z, -60.f), 60.f);
  return __builtin_amdgcn_rcpf(1.f + __expf(-z));
}
__device__ __forceinline__ float fast_tanh(float s) {
  s = fminf(fmaxf(s, -9.f), 9.f);
  float e = __expf(2.f * s);
  return (e - 1.f) * __builtin_amdgcn_rcpf(e + 1.f);
}
// 16B-granular LDS swizzle (verified round 12): spread frag-slot into lane bits.
__device__ __forceinline__ int swz(int idx16) {
  return idx16 ^ ((idx16 >> 6) & 7);
}

// ================= fragment-packed path (32x32x16) =================
#define WTP (H8 * 24 * 4 * 512)   // tanh_w hi frags
#define WOP (H8 * 8 * 8 * 512)    // out_w frags
#define XFP (NB * ND)             // x hi frags
#define NGATE (NB * H8)
#define WS_NEED3 ((size_t)(WTP + WOP + XFP) * 2 + (size_t)2 * NGATE * 4)

// blocks 0..191: tanh_w transpose; 192..255: out_w; 256..2303: x-hi pack;
// 2304..2815: exact-f32 sigmoid gates (g,p per (b,head)).
__global__ void prep3c(const float* __restrict__ tanh_w,
                       const float* __restrict__ sig_w,
                       const float* __restrict__ sig_b,
                       const float* __restrict__ out_w,
                       const float* __restrict__ x,
                       const float* __restrict__ h,
                       short* __restrict__ wtp_hi,
                       short* __restrict__ wop,
                       short* __restrict__ xfh,
                       float* __restrict__ gW, float* __restrict__ pW) {
  __shared__ float smem[14480];   // union: tile (<=4160) | xs[32*260] + ws[8*770]
  const int t = threadIdx.x;
  const int b = blockIdx.x;
  if (b < 192) {
    float* tile = smem;           // [16][132]
    int head = b / 24, ks = b % 24;
    const float* slab = tanh_w + ((size_t)head * NK + ks * 16) * NHD;
#pragma unroll
    for (int it = 0; it < 2; ++it) {
      int i = it * 256 + t;
      floatx4 v = reinterpret_cast<const floatx4*>(slab)[i];
      int r = i >> 5, c4 = i & 31;
      *reinterpret_cast<floatx4*>(&tile[r * 132 + c4 * 4]) = v;
    }
    __syncthreads();
    int ct = t >> 6, l = t & 63;
    bf16x8 hi8;
#pragma unroll
    for (int j = 0; j < 8; ++j) {
      float w = tile[((l >> 5) * 8 + j) * 132 + ct * 32 + (l & 31)];
      hi8[j] = (short)f2bf(w);
    }
    size_t dst = ((((size_t)head * 24 + ks) * 4 + ct) * 64 + l) * 8;
    *reinterpret_cast<bf16x8*>(wtp_hi + dst) = hi8;
  } else if (b < 256) {
    float* tile = smem;           // [16][260]
    int head = (b - 192) / 8, ks = (b - 192) % 8;
    const float* slab = out_w + ((size_t)head * NHD + ks * 16) * ND;
#pragma unroll
    for (int it = 0; it < 4; ++it) {
      int i = it * 256 + t;
      floatx4 v = reinterpret_cast<const floatx4*>(slab)[i];
      int r = i >> 6, c4 = i & 63;
      *reinterpret_cast<floatx4*>(&tile[r * 260 + c4 * 4]) = v;
    }
    __syncthreads();
#pragma unroll
    for (int u = 0; u < 2; ++u) {
      int idx = u * 256 + t;
      int ct = idx >> 6, l = idx & 63;
      bf16x8 o8;
#pragma unroll
      for (int j = 0; j < 8; ++j) {
        float w = tile[((l >> 5) * 8 + j) * 260 + ct * 32 + (l & 31)];
        o8[j] = (short)f2bf(w);
      }
      size_t dst = ((((size_t)head * 8 + ks) * 8 + ct) * 64 + l) * 8;
      *reinterpret_cast<bf16x8*>(wop + dst) = o8;
    }
  } else if (b < 2304) {
    // x-hi pack: one 8-float chunk per thread (524288 chunks, 2048 blocks)
    int i = (b - 256) * 256 + t;
    int bb = i >> 5, c0 = (i & 31) * 8;
    const float* xp = x + (size_t)bb * ND + c0;
    floatx4 v0 = *reinterpret_cast<const floatx4*>(xp);
    floatx4 v1 = *reinterpret_cast<const floatx4*>(xp + 4);
    bf16x8 h8;
#pragma unroll
    for (int j = 0; j < 4; ++j) {
      h8[j] = (short)f2bf(v0[j]);
      h8[4 + j] = (short)f2bf(v1[j]);
    }
    int dst = ((bb >> 5) * 16 + (c0 >> 4)) * 512 +
              (((c0 >> 3) & 1) * 32 + (bb & 31)) * 8;
    *reinterpret_cast<bf16x8*>(xfh + dst) = h8;
  } else {
    // gates: block = 32 rows x 8 heads, exact f32 dot
    float* xs = smem;             // [32][260]  padded
    float* ws = smem + 8320;      // [8][770]   padded
    int gb = b - 2304;
    long rowb = (long)gb * 32;
#pragma unroll
    for (int it = 0; it < 8; ++it) {
      int idx = it * 256 + t;     // 2048 float4
      int r = idx >> 6, c4 = idx & 63;
      floatx4 v = *reinterpret_cast<const floatx4*>(x + (rowb + r) * ND + c4 * 4);
      *reinterpret_cast<floatx4*>(&xs[r * 260 + c4 * 4]) = v;
    }
#pragma unroll
    for (int it = 0; it < 12; ++it) {
      int idx = it * 256 + t;     // 3072 float2 over sig_w's 6144 floats
      floatx2 v = *reinterpret_cast<const floatx2*>(sig_w + (size_t)idx * 2);
      int head = idx / 384;
      int rem = idx * 2 - head * 768;
      *reinterpret_cast<floatx2*>(&ws[head * 770 + rem]) = v;
    }
    __syncthreads();
    int bl = t >> 3, head = t & 7;
    const float* hrow = h + (rowb * 8 + t) * 128;   // (rowb+bl)*8+head == rowb*8+t
    const float* wh = &ws[head * 770];
    float a0 = 0.f, a1 = 0.f;
#pragma unroll 8
    for (int k4 = 0; k4 < 32; ++k4) {
      floatx4 hv = *reinterpret_cast<const floatx4*>(hrow + k4 * 4);
#pragma unroll
      for (int j = 0; j < 4; ++j) {
        floatx2 w2 = *reinterpret_cast<const floatx2*>(&wh[(k4 * 4 + j) * 2]);
        a0 += hv[j] * w2[0];
        a1 += hv[j] * w2[1];
      }
    }
    const float* xrow = &xs[bl * 260];
#pragma unroll 8
    for (int k4 = 0; k4 < 64; ++k4) {
      floatx4 xv = *reinterpret_cast<const floatx4*>(xrow + k4 * 4);
#pragma unroll
      for (int j = 0; j < 4; ++j) {
        floatx2 w2 = *reinterpret_cast<const floatx2*>(&wh[(128 + k4 * 4 + j) * 2]);
        a0 += xv[j] * w2[0];
        a1 += xv[j] * w2[1];
      }
    }
    long gi = rowb * 8 + t;
    gW[gi] = fast_sigmoid(a0 + sig_b[head * 2 + 0]);
    pW[gi] = fast_sigmoid(a1 + sig_b[head * 2 + 1]);
  }
}

// 256-thread block, 4 waves (one per 32-col quad cq); BM=64 = 2 row-groups/wave.
// g folded into h staging (split(g*h)); single-acc tanh loop; swizzled frag LDS.
__global__ __launch_bounds__(256, 4) void gru3(
    const float* __restrict__ h,
    const float* __restrict__ tanh_b, const float* __restrict__ out_b,
    const short* __restrict__ wtp_hi, const short* __restrict__ wop,
    const short* __restrict__ xfh,
    const float* __restrict__ gW, const float* __restrict__ pW,
    float* __restrict__ out, float* __restrict__ out_nh) {
  __shared__ __align__(16) short AhH[16 * 512];  // 16 KB: g*h hi frags -> new_h frags
  __shared__ __align__(16) short AhL[16 * 512];  // 16 KB: g*h lo frags
  __shared__ float pbuf[64];

  const int t = threadIdx.x;
  const int lane = t & 63;
  const int cq = t >> 6;
  const int l31 = lane & 31;
  const int lh = lane >> 5;
  const int head = (int)(blockIdx.x >> 8);
  const int rb = (int)(blockIdx.x & 255);
  const long rowbase = (long)rb * 64;

  if (t < 64) pbuf[t] = pW[(rowbase + t) * H8 + head];

  // ---- stage split(g*h) (64 rows x 128) into swizzled frag LDS; coalesced ----
#pragma unroll
  for (int it = 0; it < 4; ++it) {
    int gi = it * 256 + t;            // 0..1023
    int row = gi >> 4, kc = gi & 15;
    float g = gW[(rowbase + row) * H8 + head];
    const float* hp = h + ((rowbase + row) * H8 + head) * NHD + kc * 8;
    floatx4 v0 = *reinterpret_cast<const floatx4*>(hp);
    floatx4 v1 = *reinterpret_cast<const floatx4*>(hp + 4);
    bf16x8 hi8, lo8;
#pragma unroll
    for (int j = 0; j < 4; ++j) {
      float s0 = g * v0[j];
      unsigned short hb = f2bf(s0);
      hi8[j] = (short)hb; lo8[j] = (short)f2bf(s0 - bf2f(hb));
      float s1 = g * v1[j];
      unsigned short hb2 = f2bf(s1);
      hi8[4 + j] = (short)hb2; lo8[4 + j] = (short)f2bf(s1 - bf2f(hb2));
    }
    int rg = row >> 5, row32 = row & 31;
    int chunk = (rg * 8 + (kc >> 1)) * 64 + (kc & 1) * 32 + row32;
    int sc = swz(chunk);
    *reinterpret_cast<bf16x8*>(&AhH[sc * 8]) = hi8;
    *reinterpret_cast<bf16x8*>(&AhL[sc * 8]) = lo8;
  }
  __syncthreads();

  const short* __restrict__ xh0 = xfh + ((size_t)(rb * 2 + 0) * 16 * 512) + lane * 8;
  const short* __restrict__ xh1 = xfh + ((size_t)(rb * 2 + 1) * 16 * 512) + lane * 8;
  const short* __restrict__ bh_p = wtp_hi + (((size_t)head * 24 * 4 + cq) * 512) + lane * 8;

  // ---- tanh matmul: acc = (g*h)@Wt_h (2-term) + x@Wt_x (hi only) ----
  floatx16 acc0, acc1;
#pragma unroll
  for (int z = 0; z < 16; ++z) { acc0[z] = 0.f; acc1[z] = 0.f; }

  bf16x8 bhA = *reinterpret_cast<const bf16x8*>(bh_p);
  bf16x8 bhB = *reinterpret_cast<const bf16x8*>(bh_p + 2048);
#pragma unroll
  for (int ks = 0; ks < 8; ++ks) {
    bf16x8 bh = bhA; bhA = bhB;
    bhB = *reinterpret_cast<const bf16x8*>(bh_p + (ks + 2) * 2048);
    bf16x8 a0h = *reinterpret_cast<const bf16x8*>(&AhH[swz(ks * 64 + lane) * 8]);
    bf16x8 a0l = *reinterpret_cast<const bf16x8*>(&AhL[swz(ks * 64 + lane) * 8]);
    bf16x8 a1h = *reinterpret_cast<const bf16x8*>(&AhH[swz((8 + ks) * 64 + lane) * 8]);
    bf16x8 a1l = *reinterpret_cast<const bf16x8*>(&AhL[swz((8 + ks) * 64 + lane) * 8]);
    acc0 = __builtin_amdgcn_mfma_f32_32x32x16_bf16(a0h, bh, acc0, 0, 0, 0);
    acc0 = __builtin_amdgcn_mfma_f32_32x32x16_bf16(a0l, bh, acc0, 0, 0, 0);
    acc1 = __builtin_amdgcn_mfma_f32_32x32x16_bf16(a1h, bh, acc1, 0, 0, 0);
    acc1 = __builtin_amdgcn_mfma_f32_32x32x16_bf16(a1l, bh, acc1, 0, 0, 0);
  }
  {
    bf16x8 x0A = *reinterpret_cast<const bf16x8*>(xh0);
    bf16x8 x1A = *reinterpret_cast<const bf16x8*>(xh1);
    bf16x8 x0B = *reinterpret_cast<const bf16x8*>(xh0 + 512);
    bf16x8 x1B = *reinterpret_cast<const bf16x8*>(xh1 + 512);
#pragma unroll
    for (int xk = 0; xk < 16; ++xk) {
      const int ks = 8 + xk;
      bf16x8 bh = bhA; bhA = bhB;
      if (ks + 2 < 24) bhB = *reinterpret_cast<const bf16x8*>(bh_p + (ks + 2) * 2048);
      bf16x8 x0 = x0A, x1 = x1A;
      x0A = x0B; x1A = x1B;
      if (xk + 2 < 16) {
        x0B = *reinterpret_cast<const bf16x8*>(xh0 + (xk + 2) * 512);
        x1B = *reinterpret_cast<const bf16x8*>(xh1 + (xk + 2) * 512);
      }
      acc0 = __builtin_amdgcn_mfma_f32_32x32x16_bf16(x0, bh, acc0, 0, 0, 0);
      acc1 = __builtin_amdgcn_mfma_f32_32x32x16_bf16(x1, bh, acc1, 0, 0, 0);
    }
  }
  __syncthreads();   // all AhH/AhL reads done before new_h overwrites

  // ---- GRU epilogue: cand = tanh(acc + tb); hv from h (L2/L3-warm) ----
  const int col = cq * 32 + l31;
  const float tb = tanh_b[head * NHD + col];
  const float* __restrict__ hcol = h + (rowbase * H8 + head) * NHD + col;
#define EPI(RG, ACC)                                                          \
  {                                                                           \
    _Pragma("unroll")                                                         \
    for (int reg = 0; reg < 16; ++reg) {                                      \
      int crow = (reg & 3) + 8 * (reg >> 2) + 4 * lh;                         \
      int row = RG * 32 + crow;                                               \
      float p = pbuf[row];                                                    \
      float cand = fast_tanh(ACC[reg] + tb);                                  \
      float hv = hcol[(size_t)row * (H8 * NHD)];                              \
      float nh = hv + p * (cand - hv);                                        \
      int el16 = (RG * 8 + (col >> 4)) * 64 + ((l31 >> 3) & 1) * 32 + crow;   \
      out_nh[((rowbase + row) * H8 + head) * NHD + col] = nh;                 \
      AhH[swz(el16) * 8 + (col & 7)] = (short)f2bf(nh);                       \
    }                                                                         \
  }
  EPI(0, acc0)
  EPI(1, acc1)
#undef EPI
  __syncthreads();

  // ---- out matmul: new_h (in AhH) @ out_w, per row-group ----
  const short* __restrict__ wo_p = wop + (((size_t)head * 64 + cq * 2) * 512) + lane * 8;
  const float ob0 = out_b[head * ND + cq * 64 + l31];
  const float ob1 = out_b[head * ND + cq * 64 + 32 + l31];
#define OUTP(RG)                                                              \
  {                                                                           \
    floatx16 a3a, a3b;                                                        \
    _Pragma("unroll")                                                         \
    for (int z = 0; z < 16; ++z) { a3a[z] = 0.f; a3b[z] = 0.f; }              \
    bf16x8 w0n = *reinterpret_cast<const bf16x8*>(wo_p);                      \
    bf16x8 w1n = *reinterpret_cast<const bf16x8*>(wo_p + 512);                \
    _Pragma("unroll")                                                         \
    for (int ks = 0; ks < 8; ++ks) {                                          \
      bf16x8 w0 = w0n, w1 = w1n;                                              \
      if (ks < 7) {                                                           \
        w0n = *reinterpret_cast<const bf16x8*>(wo_p + (ks + 1) * 4096);       \
        w1n = *reinterpret_cast<const bf16x8*>(wo_p + (ks + 1) * 4096 + 512); \
      }                                                                       \
      bf16x8 a = *reinterpret_cast<const bf16x8*>(&AhH[swz((RG * 8 + ks) * 64 + lane) * 8]); \
      a3a = __builtin_amdgcn_mfma_f32_32x32x16_bf16(a, w0, a3a, 0, 0, 0);     \
      a3b = __builtin_amdgcn_mfma_f32_32x32x16_bf16(a, w1, a3b, 0, 0, 0);     \
    }                                                                         \
    _Pragma("unroll")                                                         \
    for (int reg = 0; reg < 16; ++reg) {                                      \
      int row = RG * 32 + (reg & 3) + 8 * (reg >> 2) + 4 * lh;                \
      long obase = ((rowbase + row) * H8 + head) * ND;                        \
      out[obase + cq * 64 + l31] = a3a[reg] + ob0;                            \
      out[obase + cq * 64 + 32 + l31] = a3b[reg] + ob1;                       \
    }                                                                         \
  }
  OUTP(0)
  OUTP(1)
#undef OUTP
}

// ================= fallback path (round-2 kernels) =================
#define WT_ELEMS (H8 * NK * NHD)
#define WO_ELEMS (H8 * NHD * ND)

__global__ void prep_kernel(const float* __restrict__ tanh_w,
                            const float* __restrict__ out_w,
                            short* __restrict__ wt_hi,
                            short* __restrict__ wt_lo,
                            short* __restrict__ wo) {
  const int total1 = WT_ELEMS;
  const int total2 = WO_ELEMS;
  for (int i = blockIdx.x * blockDim.x + threadIdx.x; i < total1 + total2;
       i += gridDim.x * blockDim.x) {
    if (i < total1) {
      int hh = i / (NK * NHD);
      int rem = i - hh * NK * NHD;
      int k = rem / NHD, n = rem - k * NHD;
      float w = tanh_w[i];
      unsigned short hi = f2bf(w);
      unsigned short lo = f2bf(w - bf2f(hi));
      int dst = hh * (48 * NHD * 8) + (k >> 3) * (NHD * 8) + n * 8 + (k & 7);
      wt_hi[dst] = (short)hi;
      wt_lo[dst] = (short)lo;
    } else {
      int j = i - total1;
      int hh = j / (NHD * ND);
      int rem = j - hh * NHD * ND;
      int k = rem / ND, n = rem - k * ND;
      int dst = hh * (16 * ND * 8) + (k >> 3) * (ND * 8) + n * 8 + (k & 7);
      wo[dst] = (short)f2bf(out_w[j]);
    }
  }
}

#define BM   32
#define NT   512
#define LDA 392
#define LDNH 136

__global__ __launch_bounds__(NT, 4) void gru_main(
    const float* __restrict__ x, const float* __restrict__ h,
    const float* __restrict__ sig_w, const float* __restrict__ sig_b,
    const float* __restrict__ tanh_b, const float* __restrict__ out_b,
    const short* __restrict__ wt_hi, const short* __restrict__ wt_lo,
    const short* __restrict__ wo,
    float* __restrict__ out, float* __restrict__ out_nh) {
  __shared__ __align__(16) short Ahi[BM][LDA];
  __shared__ __align__(16) short Alo[BM][LDA];
  __shared__ __align__(16) short NHL[BM][LDNH];
  __shared__ floatx2 swl[NK];
  __shared__ float gbuf[BM], pbuf[BM];

  const int t = threadIdx.x;
  const int lane = t & 63;
  const int wid = t >> 6;
  const int wrow = wid >> 2;
  const int wcol = wid & 3;
  const int ln = lane & 15;
  const int kg = lane >> 4;
  const int head = blockIdx.x & 7;
  const long rowbase = (long)(blockIdx.x >> 3) * BM;
  const int arow = wrow * 16 + ln;

#pragma unroll
  for (int i = 0; i < 4; ++i) {
    int idx = i * NT + t;
    int r = idx >> 6, c4 = idx & 63;
    floatx4 v = *reinterpret_cast<const floatx4*>(x + (rowbase + r) * ND + c4 * 4);
    bf16x4 hi, lo;
#pragma unroll
    for (int j = 0; j < 4; ++j) {
      unsigned short hb = f2bf(v[j]);
      hi[j] = (short)hb;
      lo[j] = (short)f2bf(v[j] - bf2f(hb));
    }
    *reinterpret_cast<bf16x4*>(&Ahi[r][NHD + c4 * 4]) = hi;
    *reinterpret_cast<bf16x4*>(&Alo[r][NHD + c4 * 4]) = lo;
  }
#pragma unroll
  for (int i = 0; i < 2; ++i) {
    int idx = i * NT + t;
    int r = idx >> 5, c4 = idx & 31;
    floatx4 v = *reinterpret_cast<const floatx4*>(
        h + ((rowbase + r) * H8 + head) * NHD + c4 * 4);
    bf16x4 hi, lo;
#pragma unroll
    for (int j = 0; j < 4; ++j) {
      unsigned short hb = f2bf(v[j]);
      hi[j] = (short)hb;
      lo[j] = (short)f2bf(v[j] - bf2f(hb));
    }
    *reinterpret_cast<bf16x4*>(&Ahi[r][c4 * 4]) = hi;
    *reinterpret_cast<bf16x4*>(&Alo[r][c4 * 4]) = lo;
  }
  if (t < NK)
    swl[t] = *reinterpret_cast<const floatx2*>(sig_w + ((size_t)head * NK + t) * 2);
  __syncthreads();
  {
    int r = t >> 4, u = t & 15;
    float a0 = 0.f, a1 = 0.f;
#pragma unroll
    for (int kk = 0; kk < 24; ++kk) {
      int k = u + kk * 16;
      float a = bf2f((unsigned short)Ahi[r][k]) + bf2f((unsigned short)Alo[r][k]);
      floatx2 w = swl[k];
      a0 += a * w[0];
      a1 += a * w[1];
    }
#pragma unroll
    for (int off = 1; off < 16; off <<= 1) {
      a0 += __shfl_xor(a0, off);
      a1 += __shfl_xor(a1, off);
    }
    if (u == 0) {
      gbuf[r] = fast_sigmoid(a0 + sig_b[head * 2 + 0]);
      pbuf[r] = fast_sigmoid(a1 + sig_b[head * 2 + 1]);
    }
  }
  floatx4 acc1[2] = {{0.f, 0.f, 0.f, 0.f}, {0.f, 0.f, 0.f, 0.f}};
  floatx4 acc2[2] = {{0.f, 0.f, 0.f, 0.f}, {0.f, 0.f, 0.f, 0.f}};
  const size_t wtbase = (size_t)head * (48 * NHD * 8);
#pragma unroll
  for (int ks = 0; ks < 12; ++ks) {
    bf16x8 ahi = *reinterpret_cast<const bf16x8*>(&Ahi[arow][ks * 32 + kg * 8]);
    bf16x8 alo = *reinterpret_cast<const bf16x8*>(&Alo[arow][ks * 32 + kg * 8]);
    floatx4* acc = (ks < 4) ? acc1 : acc2;
#pragma unroll
    for (int cf = 0; cf < 2; ++cf) {
      int n0 = wcol * 32 + cf * 16;
      size_t woff = wtbase + (size_t)(ks * 4 + kg) * (NHD * 8) + (size_t)(n0 + ln) * 8;
      bf16x8 bhi = *reinterpret_cast<const bf16x8*>(wt_hi + woff);
      bf16x8 blo = *reinterpret_cast<const bf16x8*>(wt_lo + woff);
      acc[cf] = __builtin_amdgcn_mfma_f32_16x16x32_bf16(ahi, bhi, acc[cf], 0, 0, 0);
      acc[cf] = __builtin_amdgcn_mfma_f32_16x16x32_bf16(alo, bhi, acc[cf], 0, 0, 0);
      acc[cf] = __builtin_amdgcn_mfma_f32_16x16x32_bf16(ahi, blo, acc[cf], 0, 0, 0);
    }
  }
  __syncthreads();
#pragma unroll
  for (int cf = 0; cf < 2; ++cf) {
    int col = wcol * 32 + cf * 16 + ln;
    float tb = tanh_b[head * NHD + col];
#pragma unroll
    for (int j = 0; j < 4; ++j) {
      int r = wrow * 16 + kg * 4 + j;
      float g = gbuf[r], p = pbuf[r];
      float s = g * acc1[cf][j] + acc2[cf][j] + tb;
      float cand = fast_tanh(s);
      float hv = bf2f((unsigned short)Ahi[r][col]) + bf2f((unsigned short)Alo[r][col]);
      float nh = hv + p * (cand - hv);
      out_nh[((rowbase + r) * H8 + head) * NHD + col] = nh;
      NHL[r][col] = (short)f2bf(nh);
    }
  }
  __syncthreads();
  floatx4 acc3[4] = {{0.f, 0.f, 0.f, 0.f}, {0.f, 0.f, 0.f, 0.f},
                     {0.f, 0.f, 0.f, 0.f}, {0.f, 0.f, 0.f, 0.f}};
  const size_t wobase = (size_t)head * (16 * ND * 8);
#pragma unroll
  for (int ks = 0; ks < 4; ++ks) {
    bf16x8 a = *reinterpret_cast<const bf16x8*>(&NHL[arow][ks * 32 + kg * 8]);
#pragma unroll
    for (int cf = 0; cf < 4; ++cf) {
      int n0 = wcol * 64 + cf * 16;
      size_t woff = wobase + (size_t)(ks * 4 + kg) * (ND * 8) + (size_t)(n0 + ln) * 8;
      bf16x8 bfr = *reinterpret_cast<const bf16x8*>(wo + woff);
      acc3[cf] = __builtin_amdgcn_mfma_f32_16x16x32_bf16(a, bfr, acc3[cf], 0, 0, 0);
    }
  }
#pragma unroll
  for (int cf = 0; cf < 4; ++cf) {
    int col = wcol * 64 + cf * 16 + ln;
    float ob = out_b[head * ND + col];
#pragma unroll
    for (int j = 0; j < 4; ++j) {
      int r = wrow * 16 + kg * 4 + j;
      out[((rowbase + r) * H8 + head) * ND + col] = acc3[cf][j] + ob;
    }
  }
}

extern "C" void kernel_launch(void* const* d_in, const int* in_sizes, int n_in,
                              void* d_out, int out_size, void* d_ws, size_t ws_size,
                              hipStream_t stream) {
  (void)in_sizes; (void)n_in; (void)out_size;
  const float* x      = (const float*)d_in[0];
  const float* h      = (const float*)d_in[1];
  const float* sig_w  = (const float*)d_in[2];
  const float* sig_b  = (const float*)d_in[3];
  const float* tanh_w = (const float*)d_in[4];
  const float* tanh_b = (const float*)d_in[5];
  const float* out_w  = (const float*)d_in[6];
  const float* out_b  = (const float*)d_in[7];

  float* out = (float*)d_out;
  float* out_nh = out + (size_t)NB * H8 * ND;

  if (ws_size >= WS_NEED3) {
    short* wtp_hi = (short*)d_ws;
    short* wop    = wtp_hi + WTP;
    short* xfh    = wop + WOP;
    float* gW     = (float*)(xfh + XFP);
    float* pW     = gW + NGATE;
    hipLaunchKernelGGL(prep3c, dim3(256 + 2048 + 512), dim3(256), 0, stream,
                       tanh_w, sig_w, sig_b, out_w, x, h,
                       wtp_hi, wop, xfh, gW, pW);
    hipLaunchKernelGGL(gru3, dim3((NB / 64) * H8), dim3(256), 0, stream,
                       h, tanh_b, out_b, wtp_hi, wop, xfh, gW, pW,
                       out, out_nh);
  } else {
    short* wt_hi = (short*)d_ws;
    short* wt_lo = wt_hi + WT_ELEMS;
    short* wo    = wt_lo + WT_ELEMS;
    hipLaunchKernelGGL(prep_kernel, dim3(512), dim3(256), 0, stream,
                       tanh_w, out_w, wt_hi, wt_lo, wo);
    hipLaunchKernelGGL(gru_main, dim3((NB / BM) * H8), dim3(NT), 0, stream,
                       x, h, sig_w, sig_b, tanh_b, out_b, wt_hi, wt_lo, wo,
                       out, out_nh);
  }
}

// Round 14
// 85.665 us; speedup vs baseline: 1.6233x; 1.0591x over previous
//
#include <hip/hip_runtime.h>
#include <math.h>

typedef short bf16x8 __attribute__((ext_vector_type(8)));
typedef short bf16x4 __attribute__((ext_vector_type(4)));
typedef float floatx4 __attribute__((ext_vector_type(4)));
typedef float floatx2 __attribute__((ext_vector_type(2)));
typedef float floatx16 __attribute__((ext_vector_type(16)));

#define NB   16384
#define H8   8
#define ND   256
#define NHD  128
#define NK   384

__device__ __forceinline__ unsigned short f2bf(float f) {
  unsigned int u = __float_as_uint(f);
  u += 0x7FFFu + ((u >> 16) & 1u);
  return (unsigned short)(u >> 16);
}
__device__ __forceinline__ float bf2f(unsigned short s) {
  return __uint_as_float(((unsigned int)s) << 16);
}
__device__ __forceinline__ float fast_sigmoid(float z) {
  z = fminf(fmaxf(z, -60.f), 60.f);
  return __builtin_amdgcn_rcpf(1.f + __expf(-z));
}
__device__ __forceinline__ float fast_tanh(float s) {
  s = fminf(fmaxf(s, -9.f), 9.f);
  float e = __expf(2.f * s);
  return (e - 1.f) * __builtin_amdgcn_rcpf(e + 1.f);
}
// 16B-granular LDS swizzle (verified round 12): spread frag-slot into lane bits.
__device__ __forceinline__ int swz(int idx16) {
  return idx16 ^ ((idx16 >> 6) & 7);
}

// ================= fragment-packed path (32x32x16) =================
#define WTP (H8 * 24 * 4 * 512)   // tanh_w hi frags
#define WOP (H8 * 8 * 8 * 512)    // out_w frags
#define XFP (NB * ND)             // x hi frags
#define NGATE (NB * H8)
#define WS_NEED3 ((size_t)(WTP + WOP + XFP) * 2 + (size_t)2 * NGATE * 4)

// blocks 0..191: tanh_w transpose; 192..255: out_w; 256..2303: x-hi pack;
// 2304..2815: exact-f32 sigmoid gates (g,p per (b,head)).
__global__ void prep3c(const float* __restrict__ tanh_w,
                       const float* __restrict__ sig_w,
                       const float* __restrict__ sig_b,
                       const float* __restrict__ out_w,
                       const float* __restrict__ x,
                       const float* __restrict__ h,
                       short* __restrict__ wtp_hi,
                       short* __restrict__ wop,
                       short* __restrict__ xfh,
                       float* __restrict__ gW, float* __restrict__ pW) {
  __shared__ float smem[14480];   // union: tile (<=4160) | xs[32*260] + ws[8*770]
  const int t = threadIdx.x;
  const int b = blockIdx.x;
  if (b < 192) {
    float* tile = smem;           // [16][132]
    int head = b / 24, ks = b % 24;
    const float* slab = tanh_w + ((size_t)head * NK + ks * 16) * NHD;
#pragma unroll
    for (int it = 0; it < 2; ++it) {
      int i = it * 256 + t;
      floatx4 v = reinterpret_cast<const floatx4*>(slab)[i];
      int r = i >> 5, c4 = i & 31;
      *reinterpret_cast<floatx4*>(&tile[r * 132 + c4 * 4]) = v;
    }
    __syncthreads();
    int ct = t >> 6, l = t & 63;
    bf16x8 hi8;
#pragma unroll
    for (int j = 0; j < 8; ++j) {
      float w = tile[((l >> 5) * 8 + j) * 132 + ct * 32 + (l & 31)];
      hi8[j] = (short)f2bf(w);
    }
    size_t dst = ((((size_t)head * 24 + ks) * 4 + ct) * 64 + l) * 8;
    *reinterpret_cast<bf16x8*>(wtp_hi + dst) = hi8;
  } else if (b < 256) {
    float* tile = smem;           // [16][260]
    int head = (b - 192) / 8, ks = (b - 192) % 8;
    const float* slab = out_w + ((size_t)head * NHD + ks * 16) * ND;
#pragma unroll
    for (int it = 0; it < 4; ++it) {
      int i = it * 256 + t;
      floatx4 v = reinterpret_cast<const floatx4*>(slab)[i];
      int r = i >> 6, c4 = i & 63;
      *reinterpret_cast<floatx4*>(&tile[r * 260 + c4 * 4]) = v;
    }
    __syncthreads();
#pragma unroll
    for (int u = 0; u < 2; ++u) {
      int idx = u * 256 + t;
      int ct = idx >> 6, l = idx & 63;
      bf16x8 o8;
#pragma unroll
      for (int j = 0; j < 8; ++j) {
        float w = tile[((l >> 5) * 8 + j) * 260 + ct * 32 + (l & 31)];
        o8[j] = (short)f2bf(w);
      }
      size_t dst = ((((size_t)head * 8 + ks) * 8 + ct) * 64 + l) * 8;
      *reinterpret_cast<bf16x8*>(wop + dst) = o8;
    }
  } else if (b < 2304) {
    // x-hi pack: one 8-float chunk per thread (524288 chunks, 2048 blocks)
    int i = (b - 256) * 256 + t;
    int bb = i >> 5, c0 = (i & 31) * 8;
    const float* xp = x + (size_t)bb * ND + c0;
    floatx4 v0 = *reinterpret_cast<const floatx4*>(xp);
    floatx4 v1 = *reinterpret_cast<const floatx4*>(xp + 4);
    bf16x8 h8;
#pragma unroll
    for (int j = 0; j < 4; ++j) {
      h8[j] = (short)f2bf(v0[j]);
      h8[4 + j] = (short)f2bf(v1[j]);
    }
    int dst = ((bb >> 5) * 16 + (c0 >> 4)) * 512 +
              (((c0 >> 3) & 1) * 32 + (bb & 31)) * 8;
    *reinterpret_cast<bf16x8*>(xfh + dst) = h8;
  } else {
    // gates: block = 32 rows x 8 heads, exact f32 dot
    float* xs = smem;             // [32][260]  padded
    float* ws = smem + 8320;      // [8][770]   padded
    int gb = b - 2304;
    long rowb = (long)gb * 32;
#pragma unroll
    for (int it = 0; it < 8; ++it) {
      int idx = it * 256 + t;     // 2048 float4
      int r = idx >> 6, c4 = idx & 63;
      floatx4 v = *reinterpret_cast<const floatx4*>(x + (rowb + r) * ND + c4 * 4);
      *reinterpret_cast<floatx4*>(&xs[r * 260 + c4 * 4]) = v;
    }
#pragma unroll
    for (int it = 0; it < 12; ++it) {
      int idx = it * 256 + t;     // 3072 float2 over sig_w's 6144 floats
      floatx2 v = *reinterpret_cast<const floatx2*>(sig_w + (size_t)idx * 2);
      int head = idx / 384;
      int rem = idx * 2 - head * 768;
      *reinterpret_cast<floatx2*>(&ws[head * 770 + rem]) = v;
    }
    __syncthreads();
    int bl = t >> 3, head = t & 7;
    const float* hrow = h + (rowb * 8 + t) * 128;   // (rowb+bl)*8+head == rowb*8+t
    const float* wh = &ws[head * 770];
    float a0 = 0.f, a1 = 0.f;
#pragma unroll 8
    for (int k4 = 0; k4 < 32; ++k4) {
      floatx4 hv = *reinterpret_cast<const floatx4*>(hrow + k4 * 4);
#pragma unroll
      for (int j = 0; j < 4; ++j) {
        floatx2 w2 = *reinterpret_cast<const floatx2*>(&wh[(k4 * 4 + j) * 2]);
        a0 += hv[j] * w2[0];
        a1 += hv[j] * w2[1];
      }
    }
    const float* xrow = &xs[bl * 260];
#pragma unroll 8
    for (int k4 = 0; k4 < 64; ++k4) {
      floatx4 xv = *reinterpret_cast<const floatx4*>(xrow + k4 * 4);
#pragma unroll
      for (int j = 0; j < 4; ++j) {
        floatx2 w2 = *reinterpret_cast<const floatx2*>(&wh[(128 + k4 * 4 + j) * 2]);
        a0 += xv[j] * w2[0];
        a1 += xv[j] * w2[1];
      }
    }
    long gi = rowb * 8 + t;
    gW[gi] = fast_sigmoid(a0 + sig_b[head * 2 + 0]);
    pW[gi] = fast_sigmoid(a1 + sig_b[head * 2 + 1]);
  }
}

// 256-thread block, 4 waves (one per 32-col quad cq); BM=64 = 2 row-groups/wave.
// g folded into h staging (split(g*h)); epilogue recovers h = (g*h)*rcp(g) from LDS.
__global__ __launch_bounds__(256, 4) void gru3(
    const float* __restrict__ h,
    const float* __restrict__ tanh_b, const float* __restrict__ out_b,
    const short* __restrict__ wtp_hi, const short* __restrict__ wop,
    const short* __restrict__ xfh,
    const float* __restrict__ gW, const float* __restrict__ pW,
    float* __restrict__ out, float* __restrict__ out_nh) {
  __shared__ __align__(16) short AhH[16 * 512];  // 16 KB: g*h hi frags -> new_h frags
  __shared__ __align__(16) short AhL[16 * 512];  // 16 KB: g*h lo frags
  __shared__ float pbuf[64], ginv[64];

  const int t = threadIdx.x;
  const int lane = t & 63;
  const int cq = t >> 6;
  const int l31 = lane & 31;
  const int lh = lane >> 5;
  const int head = (int)(blockIdx.x >> 8);
  const int rb = (int)(blockIdx.x & 255);
  const long rowbase = (long)rb * 64;

  if (t < 64) {
    pbuf[t] = pW[(rowbase + t) * H8 + head];
    float g = gW[(rowbase + t) * H8 + head];
    ginv[t] = __builtin_amdgcn_rcpf(fmaxf(g, 1e-30f));
  }

  // ---- stage split(g*h) (64 rows x 128) into swizzled frag LDS; coalesced ----
#pragma unroll
  for (int it = 0; it < 4; ++it) {
    int gi = it * 256 + t;            // 0..1023
    int row = gi >> 4, kc = gi & 15;
    float g = gW[(rowbase + row) * H8 + head];
    const float* hp = h + ((rowbase + row) * H8 + head) * NHD + kc * 8;
    floatx4 v0 = *reinterpret_cast<const floatx4*>(hp);
    floatx4 v1 = *reinterpret_cast<const floatx4*>(hp + 4);
    bf16x8 hi8, lo8;
#pragma unroll
    for (int j = 0; j < 4; ++j) {
      float s0 = g * v0[j];
      unsigned short hb = f2bf(s0);
      hi8[j] = (short)hb; lo8[j] = (short)f2bf(s0 - bf2f(hb));
      float s1 = g * v1[j];
      unsigned short hb2 = f2bf(s1);
      hi8[4 + j] = (short)hb2; lo8[4 + j] = (short)f2bf(s1 - bf2f(hb2));
    }
    int rg = row >> 5, row32 = row & 31;
    int chunk = (rg * 8 + (kc >> 1)) * 64 + (kc & 1) * 32 + row32;
    int sc = swz(chunk);
    *reinterpret_cast<bf16x8*>(&AhH[sc * 8]) = hi8;
    *reinterpret_cast<bf16x8*>(&AhL[sc * 8]) = lo8;
  }
  __syncthreads();

  const short* __restrict__ xh0 = xfh + ((size_t)(rb * 2 + 0) * 16 * 512) + lane * 8;
  const short* __restrict__ xh1 = xfh + ((size_t)(rb * 2 + 1) * 16 * 512) + lane * 8;
  const short* __restrict__ bh_p = wtp_hi + (((size_t)head * 24 * 4 + cq) * 512) + lane * 8;

  // ---- tanh matmul: acc = (g*h)@Wt_h (2-term) + x@Wt_x (hi only) ----
  floatx16 acc0, acc1;
#pragma unroll
  for (int z = 0; z < 16; ++z) { acc0[z] = 0.f; acc1[z] = 0.f; }

  bf16x8 bhA = *reinterpret_cast<const bf16x8*>(bh_p);
  bf16x8 bhB = *reinterpret_cast<const bf16x8*>(bh_p + 2048);
#pragma unroll
  for (int ks = 0; ks < 8; ++ks) {
    bf16x8 bh = bhA; bhA = bhB;
    bhB = *reinterpret_cast<const bf16x8*>(bh_p + (ks + 2) * 2048);
    bf16x8 a0h = *reinterpret_cast<const bf16x8*>(&AhH[swz(ks * 64 + lane) * 8]);
    bf16x8 a0l = *reinterpret_cast<const bf16x8*>(&AhL[swz(ks * 64 + lane) * 8]);
    bf16x8 a1h = *reinterpret_cast<const bf16x8*>(&AhH[swz((8 + ks) * 64 + lane) * 8]);
    bf16x8 a1l = *reinterpret_cast<const bf16x8*>(&AhL[swz((8 + ks) * 64 + lane) * 8]);
    acc0 = __builtin_amdgcn_mfma_f32_32x32x16_bf16(a0h, bh, acc0, 0, 0, 0);
    acc0 = __builtin_amdgcn_mfma_f32_32x32x16_bf16(a0l, bh, acc0, 0, 0, 0);
    acc1 = __builtin_amdgcn_mfma_f32_32x32x16_bf16(a1h, bh, acc1, 0, 0, 0);
    acc1 = __builtin_amdgcn_mfma_f32_32x32x16_bf16(a1l, bh, acc1, 0, 0, 0);
  }
  {
    bf16x8 x0A = *reinterpret_cast<const bf16x8*>(xh0);
    bf16x8 x1A = *reinterpret_cast<const bf16x8*>(xh1);
    bf16x8 x0B = *reinterpret_cast<const bf16x8*>(xh0 + 512);
    bf16x8 x1B = *reinterpret_cast<const bf16x8*>(xh1 + 512);
#pragma unroll
    for (int xk = 0; xk < 16; ++xk) {
      const int ks = 8 + xk;
      bf16x8 bh = bhA; bhA = bhB;
      if (ks + 2 < 24) bhB = *reinterpret_cast<const bf16x8*>(bh_p + (ks + 2) * 2048);
      bf16x8 x0 = x0A, x1 = x1A;
      x0A = x0B; x1A = x1B;
      if (xk + 2 < 16) {
        x0B = *reinterpret_cast<const bf16x8*>(xh0 + (xk + 2) * 512);
        x1B = *reinterpret_cast<const bf16x8*>(xh1 + (xk + 2) * 512);
      }
      acc0 = __builtin_amdgcn_mfma_f32_32x32x16_bf16(x0, bh, acc0, 0, 0, 0);
      acc1 = __builtin_amdgcn_mfma_f32_32x32x16_bf16(x1, bh, acc1, 0, 0, 0);
    }
  }
  __syncthreads();   // all AhH/AhL reads done before new_h overwrites

  // ---- GRU epilogue: cand = tanh(acc + tb); hv = (g*h frags) * rcp(g) ----
  const int col = cq * 32 + l31;
  const float tb = tanh_b[head * NHD + col];
#define EPI(RG, ACC)                                                          \
  {                                                                           \
    _Pragma("unroll")                                                         \
    for (int reg = 0; reg < 16; ++reg) {                                      \
      int crow = (reg & 3) + 8 * (reg >> 2) + 4 * lh;                         \
      int row = RG * 32 + crow;                                               \
      float p = pbuf[row];                                                    \
      float cand = fast_tanh(ACC[reg] + tb);                                  \
      int el16 = (RG * 8 + (col >> 4)) * 64 + ((l31 >> 3) & 1) * 32 + crow;   \
      int eb = swz(el16) * 8 + (col & 7);                                     \
      float hv = (bf2f((unsigned short)AhH[eb]) +                             \
                  bf2f((unsigned short)AhL[eb])) * ginv[row];                 \
      float nh = hv + p * (cand - hv);                                        \
      out_nh[((rowbase + row) * H8 + head) * NHD + col] = nh;                 \
      AhH[eb] = (short)f2bf(nh);                                              \
    }                                                                         \
  }
  EPI(0, acc0)
  EPI(1, acc1)
#undef EPI
  __syncthreads();

  // ---- out matmul: new_h (in AhH) @ out_w, per row-group ----
  const short* __restrict__ wo_p = wop + (((size_t)head * 64 + cq * 2) * 512) + lane * 8;
  const float ob0 = out_b[head * ND + cq * 64 + l31];
  const float ob1 = out_b[head * ND + cq * 64 + 32 + l31];
#define OUTP(RG)                                                              \
  {                                                                           \
    floatx16 a3a, a3b;                                                        \
    _Pragma("unroll")                                                         \
    for (int z = 0; z < 16; ++z) { a3a[z] = 0.f; a3b[z] = 0.f; }              \
    bf16x8 w0n = *reinterpret_cast<const bf16x8*>(wo_p);                      \
    bf16x8 w1n = *reinterpret_cast<const bf16x8*>(wo_p + 512);                \
    _Pragma("unroll")                                                         \
    for (int ks = 0; ks < 8; ++ks) {                                          \
      bf16x8 w0 = w0n, w1 = w1n;                                              \
      if (ks < 7) {                                                           \
        w0n = *reinterpret_cast<const bf16x8*>(wo_p + (ks + 1) * 4096);       \
        w1n = *reinterpret_cast<const bf16x8*>(wo_p + (ks + 1) * 4096 + 512); \
      }                                                                       \
      bf16x8 a = *reinterpret_cast<const bf16x8*>(&AhH[swz((RG * 8 + ks) * 64 + lane) * 8]); \
      a3a = __builtin_amdgcn_mfma_f32_32x32x16_bf16(a, w0, a3a, 0, 0, 0);     \
      a3b = __builtin_amdgcn_mfma_f32_32x32x16_bf16(a, w1, a3b, 0, 0, 0);     \
    }                                                                         \
    _Pragma("unroll")                                                         \
    for (int reg = 0; reg < 16; ++reg) {                                      \
      int row = RG * 32 + (reg & 3) + 8 * (reg >> 2) + 4 * lh;                \
      long obase = ((rowbase + row) * H8 + head) * ND;                        \
      out[obase + cq * 64 + l31] = a3a[reg] + ob0;                            \
      out[obase + cq * 64 + 32 + l31] = a3b[reg] + ob1;                       \
    }                                                                         \
  }
  OUTP(0)
  OUTP(1)
#undef OUTP
}

// ================= fallback path (round-2 kernels) =================
#define WT_ELEMS (H8 * NK * NHD)
#define WO_ELEMS (H8 * NHD * ND)

__global__ void prep_kernel(const float* __restrict__ tanh_w,
                            const float* __restrict__ out_w,
                            short* __restrict__ wt_hi,
                            short* __restrict__ wt_lo,
                            short* __restrict__ wo) {
  const int total1 = WT_ELEMS;
  const int total2 = WO_ELEMS;
  for (int i = blockIdx.x * blockDim.x + threadIdx.x; i < total1 + total2;
       i += gridDim.x * blockDim.x) {
    if (i < total1) {
      int hh = i / (NK * NHD);
      int rem = i - hh * NK * NHD;
      int k = rem / NHD, n = rem - k * NHD;
      float w = tanh_w[i];
      unsigned short hi = f2bf(w);
      unsigned short lo = f2bf(w - bf2f(hi));
      int dst = hh * (48 * NHD * 8) + (k >> 3) * (NHD * 8) + n * 8 + (k & 7);
      wt_hi[dst] = (short)hi;
      wt_lo[dst] = (short)lo;
    } else {
      int j = i - total1;
      int hh = j / (NHD * ND);
      int rem = j - hh * NHD * ND;
      int k = rem / ND, n = rem - k * ND;
      int dst = hh * (16 * ND * 8) + (k >> 3) * (ND * 8) + n * 8 + (k & 7);
      wo[dst] = (short)f2bf(out_w[j]);
    }
  }
}

#define BM   32
#define NT   512
#define LDA 392
#define LDNH 136

__global__ __launch_bounds__(NT, 4) void gru_main(
    const float* __restrict__ x, const float* __restrict__ h,
    const float* __restrict__ sig_w, const float* __restrict__ sig_b,
    const float* __restrict__ tanh_b, const float* __restrict__ out_b,
    const short* __restrict__ wt_hi, const short* __restrict__ wt_lo,
    const short* __restrict__ wo,
    float* __restrict__ out, float* __restrict__ out_nh) {
  __shared__ __align__(16) short Ahi[BM][LDA];
  __shared__ __align__(16) short Alo[BM][LDA];
  __shared__ __align__(16) short NHL[BM][LDNH];
  __shared__ floatx2 swl[NK];
  __shared__ float gbuf[BM], pbuf[BM];

  const int t = threadIdx.x;
  const int lane = t & 63;
  const int wid = t >> 6;
  const int wrow = wid >> 2;
  const int wcol = wid & 3;
  const int ln = lane & 15;
  const int kg = lane >> 4;
  const int head = blockIdx.x & 7;
  const long rowbase = (long)(blockIdx.x >> 3) * BM;
  const int arow = wrow * 16 + ln;

#pragma unroll
  for (int i = 0; i < 4; ++i) {
    int idx = i * NT + t;
    int r = idx >> 6, c4 = idx & 63;
    floatx4 v = *reinterpret_cast<const floatx4*>(x + (rowbase + r) * ND + c4 * 4);
    bf16x4 hi, lo;
#pragma unroll
    for (int j = 0; j < 4; ++j) {
      unsigned short hb = f2bf(v[j]);
      hi[j] = (short)hb;
      lo[j] = (short)f2bf(v[j] - bf2f(hb));
    }
    *reinterpret_cast<bf16x4*>(&Ahi[r][NHD + c4 * 4]) = hi;
    *reinterpret_cast<bf16x4*>(&Alo[r][NHD + c4 * 4]) = lo;
  }
#pragma unroll
  for (int i = 0; i < 2; ++i) {
    int idx = i * NT + t;
    int r = idx >> 5, c4 = idx & 31;
    floatx4 v = *reinterpret_cast<const floatx4*>(
        h + ((rowbase + r) * H8 + head) * NHD + c4 * 4);
    bf16x4 hi, lo;
#pragma unroll
    for (int j = 0; j < 4; ++j) {
      unsigned short hb = f2bf(v[j]);
      hi[j] = (short)hb;
      lo[j] = (short)f2bf(v[j] - bf2f(hb));
    }
    *reinterpret_cast<bf16x4*>(&Ahi[r][c4 * 4]) = hi;
    *reinterpret_cast<bf16x4*>(&Alo[r][c4 * 4]) = lo;
  }
  if (t < NK)
    swl[t] = *reinterpret_cast<const floatx2*>(sig_w + ((size_t)head * NK + t) * 2);
  __syncthreads();
  {
    int r = t >> 4, u = t & 15;
    float a0 = 0.f, a1 = 0.f;
#pragma unroll
    for (int kk = 0; kk < 24; ++kk) {
      int k = u + kk * 16;
      float a = bf2f((unsigned short)Ahi[r][k]) + bf2f((unsigned short)Alo[r][k]);
      floatx2 w = swl[k];
      a0 += a * w[0];
      a1 += a * w[1];
    }
#pragma unroll
    for (int off = 1; off < 16; off <<= 1) {
      a0 += __shfl_xor(a0, off);
      a1 += __shfl_xor(a1, off);
    }
    if (u == 0) {
      gbuf[r] = fast_sigmoid(a0 + sig_b[head * 2 + 0]);
      pbuf[r] = fast_sigmoid(a1 + sig_b[head * 2 + 1]);
    }
  }
  floatx4 acc1[2] = {{0.f, 0.f, 0.f, 0.f}, {0.f, 0.f, 0.f, 0.f}};
  floatx4 acc2[2] = {{0.f, 0.f, 0.f, 0.f}, {0.f, 0.f, 0.f, 0.f}};
  const size_t wtbase = (size_t)head * (48 * NHD * 8);
#pragma unroll
  for (int ks = 0; ks < 12; ++ks) {
    bf16x8 ahi = *reinterpret_cast<const bf16x8*>(&Ahi[arow][ks * 32 + kg * 8]);
    bf16x8 alo = *reinterpret_cast<const bf16x8*>(&Alo[arow][ks * 32 + kg * 8]);
    floatx4* acc = (ks < 4) ? acc1 : acc2;
#pragma unroll
    for (int cf = 0; cf < 2; ++cf) {
      int n0 = wcol * 32 + cf * 16;
      size_t woff = wtbase + (size_t)(ks * 4 + kg) * (NHD * 8) + (size_t)(n0 + ln) * 8;
      bf16x8 bhi = *reinterpret_cast<const bf16x8*>(wt_hi + woff);
      bf16x8 blo = *reinterpret_cast<const bf16x8*>(wt_lo + woff);
      acc[cf] = __builtin_amdgcn_mfma_f32_16x16x32_bf16(ahi, bhi, acc[cf], 0, 0, 0);
      acc[cf] = __builtin_amdgcn_mfma_f32_16x16x32_bf16(alo, bhi, acc[cf], 0, 0, 0);
      acc[cf] = __builtin_amdgcn_mfma_f32_16x16x32_bf16(ahi, blo, acc[cf], 0, 0, 0);
    }
  }
  __syncthreads();
#pragma unroll
  for (int cf = 0; cf < 2; ++cf) {
    int col = wcol * 32 + cf * 16 + ln;
    float tb = tanh_b[head * NHD + col];
#pragma unroll
    for (int j = 0; j < 4; ++j) {
      int r = wrow * 16 + kg * 4 + j;
      float g = gbuf[r], p = pbuf[r];
      float s = g * acc1[cf][j] + acc2[cf][j] + tb;
      float cand = fast_tanh(s);
      float hv = bf2f((unsigned short)Ahi[r][col]) + bf2f((unsigned short)Alo[r][col]);
      float nh = hv + p * (cand - hv);
      out_nh[((rowbase + r) * H8 + head) * NHD + col] = nh;
      NHL[r][col] = (short)f2bf(nh);
    }
  }
  __syncthreads();
  floatx4 acc3[4] = {{0.f, 0.f, 0.f, 0.f}, {0.f, 0.f, 0.f, 0.f},
                     {0.f, 0.f, 0.f, 0.f}, {0.f, 0.f, 0.f, 0.f}};
  const size_t wobase = (size_t)head * (16 * ND * 8);
#pragma unroll
  for (int ks = 0; ks < 4; ++ks) {
    bf16x8 a = *reinterpret_cast<const bf16x8*>(&NHL[arow][ks * 32 + kg * 8]);
#pragma unroll
    for (int cf = 0; cf < 4; ++cf) {
      int n0 = wcol * 64 + cf * 16;
      size_t woff = wobase + (size_t)(ks * 4 + kg) * (ND * 8) + (size_t)(n0 + ln) * 8;
      bf16x8 bfr = *reinterpret_cast<const bf16x8*>(wo + woff);
      acc3[cf] = __builtin_amdgcn_mfma_f32_16x16x32_bf16(a, bfr, acc3[cf], 0, 0, 0);
    }
  }
#pragma unroll
  for (int cf = 0; cf < 4; ++cf) {
    int col = wcol * 64 + cf * 16 + ln;
    float ob = out_b[head * ND + col];
#pragma unroll
    for (int j = 0; j < 4; ++j) {
      int r = wrow * 16 + kg * 4 + j;
      out[((rowbase + r) * H8 + head) * ND + col] = acc3[cf][j] + ob;
    }
  }
}

extern "C" void kernel_launch(void* const* d_in, const int* in_sizes, int n_in,
                              void* d_out, int out_size, void* d_ws, size_t ws_size,
                              hipStream_t stream) {
  (void)in_sizes; (void)n_in; (void)out_size;
  const float* x      = (const float*)d_in[0];
  const float* h      = (const float*)d_in[1];
  const float* sig_w  = (const float*)d_in[2];
  const float* sig_b  = (const float*)d_in[3];
  const float* tanh_w = (const float*)d_in[4];
  const float* tanh_b = (const float*)d_in[5];
  const float* out_w  = (const float*)d_in[6];
  const float* out_b  = (const float*)d_in[7];

  float* out = (float*)d_out;
  float* out_nh = out + (size_t)NB * H8 * ND;

  if (ws_size >= WS_NEED3) {
    short* wtp_hi = (short*)d_ws;
    short* wop    = wtp_hi + WTP;
    short* xfh    = wop + WOP;
    float* gW     = (float*)(xfh + XFP);
    float* pW     = gW + NGATE;
    hipLaunchKernelGGL(prep3c, dim3(256 + 2048 + 512), dim3(256), 0, stream,
                       tanh_w, sig_w, sig_b, out_w, x, h,
                       wtp_hi, wop, xfh, gW, pW);
    hipLaunchKernelGGL(gru3, dim3((NB / 64) * H8), dim3(256), 0, stream,
                       h, tanh_b, out_b, wtp_hi, wop, xfh, gW, pW,
                       out, out_nh);
  } else {
    short* wt_hi = (short*)d_ws;
    short* wt_lo = wt_hi + WT_ELEMS;
    short* wo    = wt_lo + WT_ELEMS;
    hipLaunchKernelGGL(prep_kernel, dim3(512), dim3(256), 0, stream,
                       tanh_w, out_w, wt_hi, wt_lo, wo);
    hipLaunchKernelGGL(gru_main, dim3((NB / BM) * H8), dim3(NT), 0, stream,
                       x, h, sig_w, sig_b, tanh_b, out_b, wt_hi, wt_lo, wo,
                       out, out_nh);
  }
}